// Round 7
// baseline (335.823 us; speedup 1.0000x reference)
//
#include <hip/hip_runtime.h>

typedef __bf16 bf16;
typedef __bf16 bf16x8 __attribute__((ext_vector_type(8)));
typedef __bf16 bf16x4 __attribute__((ext_vector_type(4)));
typedef float  f32x4  __attribute__((ext_vector_type(4)));

#define MFMA16 __builtin_amdgcn_mfma_f32_16x16x32_bf16

static constexpr int   BSZ   = 4;
static constexpr int   SEQL  = 2048;
static constexpr int   DM    = 1024;
static constexpr int   NHEAD = 16;
static constexpr int   DHEAD = 64;
static constexpr float SCL2  = 0.125f * 1.44269504f;   // folded into Wk at cvt

// async global->LDS, 16B per lane; LDS dest = wave-uniform base + lane*16
__device__ __forceinline__ void glds16(bf16* lds, const bf16* g) {
    __builtin_amdgcn_global_load_lds(
        (const __attribute__((address_space(1))) unsigned int*)g,
        (__attribute__((address_space(3))) unsigned int*)lds, 16, 0, 0);
}

// ---------------------------------------------------------------------------
// Mask dtype detection: flag 0=int32{0,1}, 1=byte, 2=float32, 3=bf16
__global__ void detect_mask(const unsigned int* __restrict__ m, int* __restrict__ flag) {
    __shared__ int ok[4];
    if (threadIdx.x < 4) ok[threadIdx.x] = 1;
    __syncthreads();
    for (int i = 0; i < 16; ++i) {
        unsigned int w = m[threadIdx.x * 16 + i];
        if (!(w == 0u || w == 1u)) ok[0] = 0;
        if (w & 0xFEFEFEFEu) ok[1] = 0;
        if (!(w == 0u || w == 0x3F800000u)) ok[2] = 0;
        unsigned lo = w & 0xFFFFu, hi = w >> 16;
        if (!((lo == 0u || lo == 0x3F80u) && (hi == 0u || hi == 0x3F80u))) ok[3] = 0;
    }
    __syncthreads();
    if (threadIdx.x == 0)
        *flag = ok[0] ? 0 : (ok[1] ? 1 : (ok[2] ? 2 : 3));
}

__device__ __forceinline__ bool mask_at(const void* m, int fl, long idx) {
    if (fl == 0) return ((const int*)m)[idx] != 0;
    if (fl == 1) return ((const unsigned char*)m)[idx] != 0;
    if (fl == 2) return ((const float*)m)[idx] != 0.0f;
    return ((const unsigned short*)m)[idx] != 0;
}

// mask -> row bit matrix: rb[row*32+kt] bit k = mask[row][kt*64+k]. One ballot/wave.
__global__ __launch_bounds__(256) void prep_bits(const void* __restrict__ mask,
                                                 const int* __restrict__ flagp,
                                                 unsigned long long* __restrict__ rb) {
    const int fl = *flagp;
    const int word = blockIdx.x * 4 + (threadIdx.x >> 6);
    const long base = (long)word * 64 + (threadIdx.x & 63);
    unsigned long long b = __ballot(mask_at(mask, fl, base));
    if ((threadIdx.x & 63) == 0) rb[word] = b;
}

// Rearrange row bits into MFMA-register layout words:
// wm[(qgrp*32+kt)*16 + jj*4+r] bit L = mask[qgrp*16+(L&15)][kt*64+(jj&1)*32+(L>>4)*8+(jj>>1)*4+r]
// so in flash_attn one u64 word masks exactly one (qg,jj,r) output register via
// a single sgpr-pair v_cndmask (bit index == lane id).
__global__ __launch_bounds__(256) void prep_words(
    const unsigned long long* __restrict__ rb, unsigned long long* __restrict__ wm)
{
    const int t = threadIdx.x, L = t & 63, w = t >> 6;
    const int pair = blockIdx.x * 4 + w;            // qgrp*32 + kt, 0..4095
    const int qgrp = pair >> 5, kt = pair & 31;
    const unsigned long long r0 = rb[(size_t)(qgrp * 16 + (L & 15)) * 32 + kt];
    const int lq = L >> 4;
    unsigned long long myw = 0;
    #pragma unroll
    for (int jr = 0; jr < 16; ++jr) {
        const int jj = jr >> 2, r = jr & 3;
        const int bitpos = (jj & 1) * 32 + lq * 8 + (jj >> 1) * 4 + r;
        unsigned long long bal = __ballot(((r0 >> bitpos) & 1ull) != 0ull);
        if (L == jr) myw = bal;
    }
    if (L < 16) wm[(size_t)pair * 16 + L] = myw;
}

// ---------------------------------------------------------------------------
// LayerNorm: one block per row of 1024. fp32 compute, bf16 out.
__global__ __launch_bounds__(256) void ln_kernel(
    const float* __restrict__ x, const float* __restrict__ g,
    const float* __restrict__ bta, bf16* __restrict__ y)
{
    const int row = blockIdx.x, t = threadIdx.x;
    const float4 v = ((const float4*)(x + (size_t)row * DM))[t];
    float s  = v.x + v.y + v.z + v.w;
    float ss = v.x * v.x + v.y * v.y + v.z * v.z + v.w * v.w;
    for (int m = 32; m >= 1; m >>= 1) { s += __shfl_xor(s, m); ss += __shfl_xor(ss, m); }
    __shared__ float red[8];
    const int w = t >> 6, L = t & 63;
    if (L == 0) { red[w] = s; red[4 + w] = ss; }
    __syncthreads();
    s  = red[0] + red[1] + red[2] + red[3];
    ss = red[4] + red[5] + red[6] + red[7];
    const float mu = s * (1.0f / DM);
    const float var = ss * (1.0f / DM) - mu * mu;
    const float r = rsqrtf(var + 1e-5f);
    const float4 gv = ((const float4*)g)[t];
    const float4 bv = ((const float4*)bta)[t];
    bf16x4 o;
    o[0] = (bf16)((v.x - mu) * r * gv.x + bv.x);
    o[1] = (bf16)((v.y - mu) * r * gv.y + bv.y);
    o[2] = (bf16)((v.z - mu) * r * gv.z + bv.z);
    o[3] = (bf16)((v.w - mu) * r * gv.w + bv.w);
    ((bf16x4*)(y + (size_t)row * DM))[t] = o;
}

// ---------------------------------------------------------------------------
// Transpose+convert 4 weight matrices (1024x1024 f32, KxN) into bf16 NxK.
// Wk (z==1) is pre-scaled by SCALE*log2e so flash scores are in log2 domain.
__global__ void cvt_w(const float* __restrict__ Wq, const float* __restrict__ Wk,
                      const float* __restrict__ Wv, const float* __restrict__ Wo,
                      bf16* __restrict__ Wt)
{
    __shared__ float tile[32][33];
    const int z = blockIdx.z;
    const float* src = (z == 0) ? Wq : (z == 1) ? Wk : (z == 2) ? Wv : Wo;
    const float scl = (z == 1) ? SCL2 : 1.0f;
    bf16* dst = Wt + (size_t)z * DM * DM;
    const int tx = threadIdx.x, ty = threadIdx.y;
    const int nIn = blockIdx.x * 32 + tx;
    const int kIn = blockIdx.y * 32;
    for (int i = 0; i < 32; i += 8)
        tile[ty + i][tx] = src[(size_t)(kIn + ty + i) * DM + nIn];
    __syncthreads();
    const int nOut = blockIdx.x * 32;
    const int kOut = blockIdx.y * 32 + tx;
    for (int i = 0; i < 32; i += 8)
        dst[(size_t)(nOut + ty + i) * DM + kOut] = (bf16)(tile[tx][ty + i] * scl);
}

// ---------------------------------------------------------------------------
// 256x128 GEMM core, BK=64, 512 threads (8 waves = 4M x 2N): same schedule,
// swizzle, fragment formulas and FP accumulation order as the verified
// 128x128 core -- only scaled (tile-parameter change, not a schedule edit).
// Per-FLOP staging drops 25% (6 glds/thread/K-step feed 2x output) and
// barrier crossings per FLOP halve. LDS 48KB -> 3 blocks/CU.
// LDS rows are XOR-swizzled by (row&7) on the 16B slot: store side pre-swizzles
// the GLOBAL source column (glds16 dest must stay linear), read side applies
// the same XOR. C-layout per `swapped`: unswapped: m <- lq*4+r, n <- lr;
// swapped: m <- lr, n <- lq*4+r (quad along the contiguous output axis).
__device__ __forceinline__ void gemm256_core(
    const bf16* __restrict__ A, const bf16* __restrict__ Bt,
    int m0, int n0, bool swapped, f32x4 acc[4][4], bf16* Asm, bf16* Bsm)
{
    const int t = threadIdx.x, w = t >> 6, L = t & 63;
    const int lr = L & 15, lq = L >> 4;
    const int wm = w & 3, wn = w >> 2;
    // staging: lane L -> row (L>>3) within wave's row group, 16B slot (L&7);
    // data for physical slot p of row r is logical slot p^(r&7).
    const int srow = L >> 3;
    const int scol = ((L & 7) ^ (L >> 3)) * 8;
    const bf16* Ab = A  + (size_t)(m0 + w * 32 + srow) * DM + scol;  // 8w x 32r = 256
    const bf16* Bb = Bt + (size_t)(n0 + w * 16 + srow) * DM + scol;  // 8w x 16r = 128
    bf16* AsmW = Asm + (w * 32) * 64;
    bf16* BsmW = Bsm + (w * 16) * 64;
    for (int kk = 0; kk < DM; kk += 64) {
        __syncthreads();
        glds16(AsmW,           Ab + kk);
        glds16(AsmW +  8 * 64, Ab + (size_t) 8 * DM + kk);
        glds16(AsmW + 16 * 64, Ab + (size_t)16 * DM + kk);
        glds16(AsmW + 24 * 64, Ab + (size_t)24 * DM + kk);
        glds16(BsmW,           Bb + kk);
        glds16(BsmW +  8 * 64, Bb + (size_t) 8 * DM + kk);
        __syncthreads();
        #pragma unroll
        for (int ks = 0; ks < 2; ++ks) {
            bf16x8 af[4], bf_[4];
            #pragma unroll
            for (int i = 0; i < 4; ++i) {
                const int ra = wm * 64 + i * 16 + lr;                // 0..255
                af[i] = *(const bf16x8*)(Asm + ra * 64 + ((((ks << 2) | lq) ^ (lr & 7)) << 3));
            }
            #pragma unroll
            for (int j = 0; j < 4; ++j) {
                const int rb2 = wn * 64 + j * 16 + lr;               // 0..127
                bf_[j] = *(const bf16x8*)(Bsm + rb2 * 64 + ((((ks << 2) | lq) ^ (lr & 7)) << 3));
            }
            if (!swapped) {
                #pragma unroll
                for (int i = 0; i < 4; ++i)
                    #pragma unroll
                    for (int j = 0; j < 4; ++j)
                        acc[i][j] = MFMA16(af[i], bf_[j], acc[i][j], 0, 0, 0);
            } else {
                #pragma unroll
                for (int i = 0; i < 4; ++i)
                    #pragma unroll
                    for (int j = 0; j < 4; ++j)
                        acc[i][j] = MFMA16(bf_[j], af[i], acc[i][j], 0, 0, 0);
            }
        }
    }
}

// Fused QKV projection, one dispatch: y -> (z = y>>3, n0 = (y&7)*128).
// z=0,1 -> Q,K in (b,h,s,d) via SWAPPED C (quad along d -> bf16x4 stores);
// z=2   -> V^T in (b,h,d,s) via UNSWAPPED C (quad along s -> bf16x4 stores).
__global__ __launch_bounds__(512) void qkv256(
    const bf16* __restrict__ qn, const bf16* __restrict__ Wt,
    bf16* __restrict__ Qb, bf16* __restrict__ Kb, bf16* __restrict__ Vtb)
{
    __shared__ __align__(16) bf16 Asm[256 * 64];   // 32 KB
    __shared__ __align__(16) bf16 Bsm[128 * 64];   // 16 KB
    const int ny = blockIdx.y;
    const int z = ny >> 3;
    const int m0 = blockIdx.x * 256, n0 = (ny & 7) * 128;
    f32x4 acc[4][4] = {};
    gemm256_core(qn, Wt + (size_t)z * DM * DM, m0, n0, z < 2, acc, Asm, Bsm);
    const int t = threadIdx.x, L = t & 63, w = t >> 6;
    const int wm = w & 3, wn = w >> 2, lr = L & 15, lq = L >> 4;
    if (z < 2) {
        bf16* dst = z ? Kb : Qb;
        #pragma unroll
        for (int i = 0; i < 4; ++i) {
            const int m = m0 + wm * 64 + i * 16 + lr;        // b*2048+s (fixed/lane)
            const int b = m >> 11, s = m & 2047;
            #pragma unroll
            for (int j = 0; j < 4; ++j) {
                const int n = n0 + wn * 64 + j * 16 + lq * 4; // h*64+d base
                const int h = n >> 6, d = n & 63;
                bf16x4 ov;
                #pragma unroll
                for (int r = 0; r < 4; ++r) ov[r] = (bf16)acc[i][j][r];
                *(bf16x4*)(dst + (((size_t)b * NHEAD + h) * SEQL + s) * DHEAD + d) = ov;
            }
        }
    } else {
        #pragma unroll
        for (int j = 0; j < 4; ++j) {
            const int n = n0 + wn * 64 + j * 16 + lr;        // h*64+d (fixed/lane)
            const int h = n >> 6, d = n & 63;
            #pragma unroll
            for (int i = 0; i < 4; ++i) {
                const int m = m0 + wm * 64 + i * 16 + lq * 4; // b*2048+s base
                const int b = m >> 11, s = m & 2047;
                bf16x4 ov;
                #pragma unroll
                for (int r = 0; r < 4; ++r) ov[r] = (bf16)acc[i][j][r];
                *(bf16x4*)(Vtb + (((size_t)b * NHEAD + h) * DHEAD + d) * SEQL + s) = ov;
            }
        }
    }
}

// Output projection + residual (fp32 out). SWAPPED C: quad along n -> float4.
__global__ __launch_bounds__(512) void out256(
    const bf16* __restrict__ vec, const bf16* __restrict__ Wot,
    const bf16* __restrict__ qnb, float* __restrict__ out)
{
    __shared__ __align__(16) bf16 Asm[256 * 64];
    __shared__ __align__(16) bf16 Bsm[128 * 64];
    const int m0 = blockIdx.x * 256, n0 = blockIdx.y * 128;
    f32x4 acc[4][4] = {};
    gemm256_core(vec, Wot, m0, n0, true, acc, Asm, Bsm);
    const int t = threadIdx.x, L = t & 63, w = t >> 6;
    const int wm = w & 3, wn = w >> 2, lr = L & 15, lq = L >> 4;
    #pragma unroll
    for (int i = 0; i < 4; ++i) {
        const int m = m0 + wm * 64 + i * 16 + lr;            // row (fixed/lane)
        #pragma unroll
        for (int j = 0; j < 4; ++j) {
            const int n = n0 + wn * 64 + j * 16 + lq * 4;    // col base
            const size_t idx = (size_t)m * DM + n;
            const bf16x4 q4 = *(const bf16x4*)(qnb + idx);
            float4 ov;
            ov.x = acc[i][j][0] + (float)q4[0];
            ov.y = acc[i][j][1] + (float)q4[1];
            ov.z = acc[i][j][2] + (float)q4[2];
            ov.w = acc[i][j][3] + (float)q4[3];
            *(float4*)(out + idx) = ov;
        }
    }
}

// ---------------------------------------------------------------------------
// Flash attention v11 (R4, verified 108us): LDS double-buffer, one barrier per
// tile, reg-staged K/V prefetch, SGPR-mask cndmask, setprio on MFMA clusters.
// 1D grid 1024; 4 waves; wave = 32 q-rows. 36 KB LDS. UNCHANGED from R6.
__global__ __launch_bounds__(256) void flash_attn(
    const bf16* __restrict__ Qb, const bf16* __restrict__ Kb,
    const bf16* __restrict__ Vtb, const unsigned long long* __restrict__ mb,
    bf16* __restrict__ vec)
{
    __shared__ __align__(16) bf16 Ksm [2][64 * 72];    // [buf][slot(key)][d]
    __shared__ __align__(16) bf16 Vtsm[2][64 * 72];    // [buf][d][key]

    const int t = threadIdx.x, w = t >> 6, L = t & 63;
    const int lr = L & 15, lq = L >> 4;
    // XCD swizzle: slot = bid&7 fixed per bh -> K/V stay in one XCD's L2
    const int bid = blockIdx.x;
    const int slot = bid & 7, rest = bid >> 3;
    const int qblk = rest & 15;
    const int bh = ((rest >> 4) << 3) + slot;
    const int b = bh >> 4, h = bh & 15;
    const int q0 = qblk * 128 + w * 32;

    const bf16* Qh  = Qb  + (size_t)bh * SEQL * DHEAD;
    const bf16* Kh  = Kb  + (size_t)bh * SEQL * DHEAD;
    const bf16* Vth = Vtb + (size_t)bh * DHEAD * SEQL;

    // Q fragments: B-layout [n=qrow][k=d], resident. [qg][ks]
    bf16x8 qf[2][2];
    #pragma unroll
    for (int qg = 0; qg < 2; ++qg)
        #pragma unroll
        for (int ks = 0; ks < 2; ++ks)
            qf[qg][ks] = *(const bf16x8*)(Qh + (size_t)(q0 + qg * 16 + lr) * DHEAD + ks * 32 + lq * 8);

    // wave-uniform mask-word bases: qgrp stride = 32 kt * 16 words = 512
    const int qgrp0 = __builtin_amdgcn_readfirstlane(q0 >> 4);
    const unsigned long long* wm0 = mb + (size_t)qgrp0 * 512;
    const unsigned long long* wm1 = wm0 + 512;

    f32x4 o[4][2] = {};                      // O^T acc: [dgroup][qg]
    f32x4 lacc[2] = {};                      // row-sum acc via ones-MFMA

    const bf16 one = (bf16)1.0f;
    const bf16x8 ones8 = {one, one, one, one, one, one, one, one};
    const float fz = 0.0f;                   // VGPR zero for cndmask

    // staging: lane sr reads K row sr / Vt row sr; K goes to permuted slot row
    const int sr = t >> 2, sc = (t & 3) * 16;
    const int zrow = ((sr >> 2) & 1) * 32 + ((sr >> 5) & 1) * 16 + ((sr >> 3) & 3) * 4 + (sr & 3);
    constexpr int NT = SEQL / 64;
    bf16x8 kreg[2], vreg[2];

    // --- prologue: tile 0 -> regs -> buf0; tile 1 -> regs; one barrier
    kreg[0] = *(const bf16x8*)(Kh  + (size_t)sr * DHEAD + sc);
    kreg[1] = *(const bf16x8*)(Kh  + (size_t)sr * DHEAD + sc + 8);
    vreg[0] = *(const bf16x8*)(Vth + (size_t)sr * SEQL + sc);
    vreg[1] = *(const bf16x8*)(Vth + (size_t)sr * SEQL + sc + 8);
    *(bf16x8*)(Ksm[0]  + zrow * 72 + sc)     = kreg[0];
    *(bf16x8*)(Ksm[0]  + zrow * 72 + sc + 8) = kreg[1];
    *(bf16x8*)(Vtsm[0] + sr * 72 + sc)       = vreg[0];
    *(bf16x8*)(Vtsm[0] + sr * 72 + sc + 8)   = vreg[1];
    kreg[0] = *(const bf16x8*)(Kh  + (size_t)(64 + sr) * DHEAD + sc);
    kreg[1] = *(const bf16x8*)(Kh  + (size_t)(64 + sr) * DHEAD + sc + 8);
    vreg[0] = *(const bf16x8*)(Vth + (size_t)sr * SEQL + 64 + sc);
    vreg[1] = *(const bf16x8*)(Vth + (size_t)sr * SEQL + 64 + sc + 8);
    __syncthreads();

    for (int kt = 0; kt < NT; ++kt) {
        const int cur = kt & 1;
        const bf16* Kc = Ksm[cur];
        const bf16* Vc = Vtsm[cur];

        // ---- S^T = K·Q^T (K pre-scaled; rows permuted so C-layout = B-frag)
        f32x4 s[4][2] = {};
        #pragma unroll
        for (int ks = 0; ks < 2; ++ks) {
            bf16x8 kf[4];
            #pragma unroll
            for (int jj = 0; jj < 4; ++jj)
                kf[jj] = *(const bf16x8*)(Kc + (jj * 16 + lr) * 72 + ks * 32 + lq * 8);
            __builtin_amdgcn_s_setprio(1);
            #pragma unroll
            for (int jj = 0; jj < 4; ++jj)
                #pragma unroll
                for (int qg = 0; qg < 2; ++qg)
                    s[jj][qg] = MFMA16(kf[jj], qf[qg][ks], s[jj][qg], 0, 0, 0);
            __builtin_amdgcn_s_setprio(0);
        }

        // ---- stage tile kt+1 (regs, loaded last iter) -> alt buffer; these
        // ds_writes drain under the exp/cndmask VALU below. Then prefetch kt+2.
        if (kt + 1 < NT) {
            bf16* Ka = Ksm[cur ^ 1];
            bf16* Va = Vtsm[cur ^ 1];
            *(bf16x8*)(Ka + zrow * 72 + sc)     = kreg[0];
            *(bf16x8*)(Ka + zrow * 72 + sc + 8) = kreg[1];
            *(bf16x8*)(Va + sr * 72 + sc)       = vreg[0];
            *(bf16x8*)(Va + sr * 72 + sc + 8)   = vreg[1];
            if (kt + 2 < NT) {
                const int kb2 = (kt + 2) * 64;
                kreg[0] = *(const bf16x8*)(Kh  + (size_t)(kb2 + sr) * DHEAD + sc);
                kreg[1] = *(const bf16x8*)(Kh  + (size_t)(kb2 + sr) * DHEAD + sc + 8);
                vreg[0] = *(const bf16x8*)(Vth + (size_t)sr * SEQL + kb2 + sc);
                vreg[1] = *(const bf16x8*)(Vth + (size_t)sr * SEQL + kb2 + sc + 8);
            }
        }

        // ---- exp2 -> sgpr-mask cndmask -> pack.
        // s[jj][qg][r] holds key = (jj&1)*32 + lq*8 + (jj>>1)*4 + r; word
        // wp[jj*4+r] bit L masks exactly this register's lane-L element.
        bf16x8 pf[2][2];
        #pragma unroll
        for (int qg = 0; qg < 2; ++qg) {
            const unsigned long long* wp = (qg ? wm1 : wm0) + kt * 16;
            #pragma unroll
            for (int ks = 0; ks < 2; ++ks) {
                bf16x8 pv;
                #pragma unroll
                for (int r = 0; r < 4; ++r) {
                    float e0 = __builtin_amdgcn_exp2f(s[ks][qg][r]);
                    float e1 = __builtin_amdgcn_exp2f(s[2 + ks][qg][r]);
                    float z0, z1;
                    asm("v_cndmask_b32 %0, %1, %2, %3"
                        : "=v"(z0) : "v"(e0), "v"(fz), "s"(wp[ks * 4 + r]));
                    asm("v_cndmask_b32 %0, %1, %2, %3"
                        : "=v"(z1) : "v"(e1), "v"(fz), "s"(wp[(2 + ks) * 4 + r]));
                    pv[r]     = (bf16)z0;
                    pv[4 + r] = (bf16)z1;
                }
                pf[qg][ks] = pv;
            }
        }

        // ---- l += 1·P  and  O^T += V^T·P  (P in registers, reads cur buf)
        __builtin_amdgcn_s_setprio(1);
        #pragma unroll
        for (int ks = 0; ks < 2; ++ks) {
            #pragma unroll
            for (int qg = 0; qg < 2; ++qg)
                lacc[qg] = MFMA16(ones8, pf[qg][ks], lacc[qg], 0, 0, 0);
            #pragma unroll
            for (int dg = 0; dg < 4; ++dg) {
                bf16x8 vf = *(const bf16x8*)(Vc + (dg * 16 + lr) * 72 + ks * 32 + lq * 8);
                #pragma unroll
                for (int qg = 0; qg < 2; ++qg)
                    o[dg][qg] = MFMA16(vf, pf[qg][ks], o[dg][qg], 0, 0, 0);
            }
        }
        __builtin_amdgcn_s_setprio(0);

        // one barrier per tile: writes to alt buffer become visible; last
        // iteration has no writers so no barrier needed.
        if (kt + 1 < NT) __syncthreads();
    }

    // ---- epilogue: vec[b][s][h*64+d]; lane qrow=lr, d=dg*16+lq*4+r -> b64 stores
    #pragma unroll
    for (int qg = 0; qg < 2; ++qg) {
        const float rl = 1.0f / lacc[qg][0];
        const size_t rowb = ((size_t)b * SEQL + q0 + qg * 16 + lr) * DM + h * DHEAD;
        #pragma unroll
        for (int dg = 0; dg < 4; ++dg) {
            bf16x4 ov;
            #pragma unroll
            for (int r = 0; r < 4; ++r) ov[r] = (bf16)(o[dg][qg][r] * rl);
            *(bf16x4*)(vec + rowb + dg * 16 + lq * 4) = ov;
        }
    }
}

// ---------------------------------------------------------------------------
extern "C" void kernel_launch(void* const* d_in, const int* in_sizes, int n_in,
                              void* d_out, int out_size, void* d_ws, size_t ws_size,
                              hipStream_t stream)
{
    const float* qin   = (const float*)d_in[0];
    const void*  mask  = d_in[1];
    const float* Wq    = (const float*)d_in[2];
    const float* Wk    = (const float*)d_in[3];
    const float* Wv    = (const float*)d_in[4];
    const float* Wo    = (const float*)d_in[5];
    const float* gamma = (const float*)d_in[6];
    const float* beta  = (const float*)d_in[7];
    float* out = (float*)d_out;

    char* w = (char*)d_ws;
    int*  flag = (int*)w;
    bf16* qnb  = (bf16*)(w + 256);                 // 8192x1024 bf16  (16 MB)
    bf16* Wt   = qnb + (size_t)8192 * 1024;        // 4x 1024x1024 bf16 (8 MB)
    bf16* Qb   = Wt + (size_t)4 * 1024 * 1024;     // (b,h,s,d)  (16 MB)
    bf16* Kb   = Qb + (size_t)8192 * 1024;         // (b,h,s,d)  (16 MB)
    bf16* Vtb  = Kb + (size_t)8192 * 1024;         // (b,h,d,s)  (16 MB)
    bf16* vec  = Vtb + (size_t)8192 * 1024;        // (b,s,h*d)  (16 MB)
    unsigned long long* rbits  = (unsigned long long*)(vec + (size_t)8192 * 1024); // 512 KB
    unsigned long long* mwords = rbits + 65536;                                    // 512 KB

    detect_mask<<<1, 256, 0, stream>>>((const unsigned int*)mask, flag);
    prep_bits<<<SEQL * (SEQL / 64) / 4, 256, 0, stream>>>(mask, flag, rbits);
    prep_words<<<1024, 256, 0, stream>>>(rbits, mwords);
    ln_kernel<<<8192, 256, 0, stream>>>(qin, gamma, beta, qnb);
    cvt_w<<<dim3(32, 32, 4), dim3(32, 8), 0, stream>>>(Wq, Wk, Wv, Wo, Wt);
    qkv256<<<dim3(32, 24), 512, 0, stream>>>(qnb, Wt, Qb, Kb, Vtb);
    flash_attn<<<1024, 256, 0, stream>>>(Qb, Kb, Vtb, mwords, vec);
    out256<<<dim3(32, 8), 512, 0, stream>>>(vec, Wt + (size_t)3 * 1024 * 1024, qnb, out);
}

// Round 8
// 325.786 us; speedup vs baseline: 1.0308x; 1.0308x over previous
//
#include <hip/hip_runtime.h>

typedef __bf16 bf16;
typedef __bf16 bf16x8 __attribute__((ext_vector_type(8)));
typedef __bf16 bf16x4 __attribute__((ext_vector_type(4)));
typedef float  f32x4  __attribute__((ext_vector_type(4)));

#define MFMA16 __builtin_amdgcn_mfma_f32_16x16x32_bf16

static constexpr int   BSZ   = 4;
static constexpr int   SEQL  = 2048;
static constexpr int   DM    = 1024;
static constexpr int   NHEAD = 16;
static constexpr int   DHEAD = 64;
static constexpr float SCL2  = 0.125f * 1.44269504f;   // folded into Wk at cvt

// async global->LDS, 16B per lane; LDS dest = wave-uniform base + lane*16
__device__ __forceinline__ void glds16(bf16* lds, const bf16* g) {
    __builtin_amdgcn_global_load_lds(
        (const __attribute__((address_space(1))) unsigned int*)g,
        (__attribute__((address_space(3))) unsigned int*)lds, 16, 0, 0);
}

// ---------------------------------------------------------------------------
// Mask dtype detection: flag 0=int32{0,1}, 1=byte, 2=float32, 3=bf16
__global__ void detect_mask(const unsigned int* __restrict__ m, int* __restrict__ flag) {
    __shared__ int ok[4];
    if (threadIdx.x < 4) ok[threadIdx.x] = 1;
    __syncthreads();
    for (int i = 0; i < 16; ++i) {
        unsigned int w = m[threadIdx.x * 16 + i];
        if (!(w == 0u || w == 1u)) ok[0] = 0;
        if (w & 0xFEFEFEFEu) ok[1] = 0;
        if (!(w == 0u || w == 0x3F800000u)) ok[2] = 0;
        unsigned lo = w & 0xFFFFu, hi = w >> 16;
        if (!((lo == 0u || lo == 0x3F80u) && (hi == 0u || hi == 0x3F80u))) ok[3] = 0;
    }
    __syncthreads();
    if (threadIdx.x == 0)
        *flag = ok[0] ? 0 : (ok[1] ? 1 : (ok[2] ? 2 : 3));
}

__device__ __forceinline__ bool mask_at(const void* m, int fl, long idx) {
    if (fl == 0) return ((const int*)m)[idx] != 0;
    if (fl == 1) return ((const unsigned char*)m)[idx] != 0;
    if (fl == 2) return ((const float*)m)[idx] != 0.0f;
    return ((const unsigned short*)m)[idx] != 0;
}

// mask -> row bit matrix: rb[row*32+kt] bit k = mask[row][kt*64+k]. One ballot/wave.
__global__ __launch_bounds__(256) void prep_bits(const void* __restrict__ mask,
                                                 const int* __restrict__ flagp,
                                                 unsigned long long* __restrict__ rb) {
    const int fl = *flagp;
    const int word = blockIdx.x * 4 + (threadIdx.x >> 6);
    const long base = (long)word * 64 + (threadIdx.x & 63);
    unsigned long long b = __ballot(mask_at(mask, fl, base));
    if ((threadIdx.x & 63) == 0) rb[word] = b;
}

// Rearrange row bits into MFMA-register layout words:
// wm[(qgrp*32+kt)*16 + jj*4+r] bit L = mask[qgrp*16+(L&15)][kt*64+(jj&1)*32+(L>>4)*8+(jj>>1)*4+r]
// so in flash_attn one u64 word masks exactly one (qg,jj,r) output register via
// a single sgpr-pair v_cndmask (bit index == lane id).
__global__ __launch_bounds__(256) void prep_words(
    const unsigned long long* __restrict__ rb, unsigned long long* __restrict__ wm)
{
    const int t = threadIdx.x, L = t & 63, w = t >> 6;
    const int pair = blockIdx.x * 4 + w;            // qgrp*32 + kt, 0..4095
    const int qgrp = pair >> 5, kt = pair & 31;
    const unsigned long long r0 = rb[(size_t)(qgrp * 16 + (L & 15)) * 32 + kt];
    const int lq = L >> 4;
    unsigned long long myw = 0;
    #pragma unroll
    for (int jr = 0; jr < 16; ++jr) {
        const int jj = jr >> 2, r = jr & 3;
        const int bitpos = (jj & 1) * 32 + lq * 8 + (jj >> 1) * 4 + r;
        unsigned long long bal = __ballot(((r0 >> bitpos) & 1ull) != 0ull);
        if (L == jr) myw = bal;
    }
    if (L < 16) wm[(size_t)pair * 16 + L] = myw;
}

// ---------------------------------------------------------------------------
// LayerNorm: one block per row of 1024. fp32 compute, bf16 out.
__global__ __launch_bounds__(256) void ln_kernel(
    const float* __restrict__ x, const float* __restrict__ g,
    const float* __restrict__ bta, bf16* __restrict__ y)
{
    const int row = blockIdx.x, t = threadIdx.x;
    const float4 v = ((const float4*)(x + (size_t)row * DM))[t];
    float s  = v.x + v.y + v.z + v.w;
    float ss = v.x * v.x + v.y * v.y + v.z * v.z + v.w * v.w;
    for (int m = 32; m >= 1; m >>= 1) { s += __shfl_xor(s, m); ss += __shfl_xor(ss, m); }
    __shared__ float red[8];
    const int w = t >> 6, L = t & 63;
    if (L == 0) { red[w] = s; red[4 + w] = ss; }
    __syncthreads();
    s  = red[0] + red[1] + red[2] + red[3];
    ss = red[4] + red[5] + red[6] + red[7];
    const float mu = s * (1.0f / DM);
    const float var = ss * (1.0f / DM) - mu * mu;
    const float r = rsqrtf(var + 1e-5f);
    const float4 gv = ((const float4*)g)[t];
    const float4 bv = ((const float4*)bta)[t];
    bf16x4 o;
    o[0] = (bf16)((v.x - mu) * r * gv.x + bv.x);
    o[1] = (bf16)((v.y - mu) * r * gv.y + bv.y);
    o[2] = (bf16)((v.z - mu) * r * gv.z + bv.z);
    o[3] = (bf16)((v.w - mu) * r * gv.w + bv.w);
    ((bf16x4*)(y + (size_t)row * DM))[t] = o;
}

// ---------------------------------------------------------------------------
// Transpose+convert 4 weight matrices (1024x1024 f32, KxN) into bf16 NxK.
// Wk (z==1) is pre-scaled by SCALE*log2e so flash scores are in log2 domain.
__global__ void cvt_w(const float* __restrict__ Wq, const float* __restrict__ Wk,
                      const float* __restrict__ Wv, const float* __restrict__ Wo,
                      bf16* __restrict__ Wt)
{
    __shared__ float tile[32][33];
    const int z = blockIdx.z;
    const float* src = (z == 0) ? Wq : (z == 1) ? Wk : (z == 2) ? Wv : Wo;
    const float scl = (z == 1) ? SCL2 : 1.0f;
    bf16* dst = Wt + (size_t)z * DM * DM;
    const int tx = threadIdx.x, ty = threadIdx.y;
    const int nIn = blockIdx.x * 32 + tx;
    const int kIn = blockIdx.y * 32;
    for (int i = 0; i < 32; i += 8)
        tile[ty + i][tx] = src[(size_t)(kIn + ty + i) * DM + nIn];
    __syncthreads();
    const int nOut = blockIdx.x * 32;
    const int kOut = blockIdx.y * 32 + tx;
    for (int i = 0; i < 32; i += 8)
        dst[(size_t)(nOut + ty + i) * DM + kOut] = (bf16)(tile[tx][ty + i] * scl);
}

// ---------------------------------------------------------------------------
// 128x128 GEMM core, BK=64 (R6, verified): A (MxK rm), Bt (NxK rm),
// global_load_lds staging. LDS rows XOR-swizzled by (row&7) on the 16B slot:
// store side pre-swizzles the GLOBAL source column (glds16 dest stays linear),
// read side applies the same XOR -> b128 8-cycle floor.
// C-layout per `swapped`: unswapped: m <- lq*4+r, n <- lr;
// swapped: m <- lr, n <- lq*4+r (quad along the contiguous output axis).
__device__ __forceinline__ void gemm128_core(
    const bf16* __restrict__ A, const bf16* __restrict__ Bt,
    int m0, int n0, bool swapped, f32x4 acc[4][4], bf16* Asm, bf16* Bsm)
{
    const int t = threadIdx.x, w = t >> 6, L = t & 63;
    const int lr = L & 15, lq = L >> 4;
    const int wm = w & 1, wn = w >> 1;
    const int srow = L >> 3;
    const int scol = ((L & 7) ^ (L >> 3)) * 8;
    const bf16* Ab = A  + (size_t)(m0 + w * 32 + srow) * DM + scol;
    const bf16* Bb = Bt + (size_t)(n0 + w * 32 + srow) * DM + scol;
    bf16* AsmW = Asm + (w * 32) * 64;
    bf16* BsmW = Bsm + (w * 32) * 64;
    for (int kk = 0; kk < DM; kk += 64) {
        __syncthreads();
        glds16(AsmW,           Ab + kk);
        glds16(AsmW +  8 * 64, Ab + (size_t) 8 * DM + kk);
        glds16(AsmW + 16 * 64, Ab + (size_t)16 * DM + kk);
        glds16(AsmW + 24 * 64, Ab + (size_t)24 * DM + kk);
        glds16(BsmW,           Bb + kk);
        glds16(BsmW +  8 * 64, Bb + (size_t) 8 * DM + kk);
        glds16(BsmW + 16 * 64, Bb + (size_t)16 * DM + kk);
        glds16(BsmW + 24 * 64, Bb + (size_t)24 * DM + kk);
        __syncthreads();
        #pragma unroll
        for (int ks = 0; ks < 2; ++ks) {
            bf16x8 af[4], bf_[4];
            #pragma unroll
            for (int i = 0; i < 4; ++i) {
                const int ra = wm * 64 + i * 16 + lr;
                af[i] = *(const bf16x8*)(Asm + ra * 64 + ((((ks << 2) | lq) ^ (lr & 7)) << 3));
            }
            #pragma unroll
            for (int j = 0; j < 4; ++j) {
                const int rb2 = wn * 64 + j * 16 + lr;
                bf_[j] = *(const bf16x8*)(Bsm + rb2 * 64 + ((((ks << 2) | lq) ^ (lr & 7)) << 3));
            }
            if (!swapped) {
                #pragma unroll
                for (int i = 0; i < 4; ++i)
                    #pragma unroll
                    for (int j = 0; j < 4; ++j)
                        acc[i][j] = MFMA16(af[i], bf_[j], acc[i][j], 0, 0, 0);
            } else {
                #pragma unroll
                for (int i = 0; i < 4; ++i)
                    #pragma unroll
                    for (int j = 0; j < 4; ++j)
                        acc[i][j] = MFMA16(bf_[j], af[i], acc[i][j], 0, 0, 0);
            }
        }
    }
}

// Fused QKV projection, one dispatch: y -> (z = y>>3, n0 = (y&7)*128).
// z=0,1 -> Q,K in (b,h,s,d) via SWAPPED C (quad along d -> bf16x4 stores);
// z=2   -> V^T in (b,h,d,s) via UNSWAPPED C (quad along s -> bf16x4 stores).
__global__ __launch_bounds__(256) void qkv128(
    const bf16* __restrict__ qn, const bf16* __restrict__ Wt,
    bf16* __restrict__ Qb, bf16* __restrict__ Kb, bf16* __restrict__ Vtb)
{
    __shared__ __align__(16) bf16 Asm[128 * 64];
    __shared__ __align__(16) bf16 Bsm[128 * 64];
    const int ny = blockIdx.y;
    const int z = ny >> 3;
    const int m0 = blockIdx.x * 128, n0 = (ny & 7) * 128;
    f32x4 acc[4][4] = {};
    gemm128_core(qn, Wt + (size_t)z * DM * DM, m0, n0, z < 2, acc, Asm, Bsm);
    const int t = threadIdx.x, L = t & 63, w = t >> 6;
    const int wm = w & 1, wn = w >> 1, lr = L & 15, lq = L >> 4;
    if (z < 2) {
        bf16* dst = z ? Kb : Qb;
        #pragma unroll
        for (int i = 0; i < 4; ++i) {
            const int m = m0 + wm * 64 + i * 16 + lr;        // b*2048+s (fixed/lane)
            const int b = m >> 11, s = m & 2047;
            #pragma unroll
            for (int j = 0; j < 4; ++j) {
                const int n = n0 + wn * 64 + j * 16 + lq * 4; // h*64+d base
                const int h = n >> 6, d = n & 63;
                bf16x4 ov;
                #pragma unroll
                for (int r = 0; r < 4; ++r) ov[r] = (bf16)acc[i][j][r];
                *(bf16x4*)(dst + (((size_t)b * NHEAD + h) * SEQL + s) * DHEAD + d) = ov;
            }
        }
    } else {
        #pragma unroll
        for (int j = 0; j < 4; ++j) {
            const int n = n0 + wn * 64 + j * 16 + lr;        // h*64+d (fixed/lane)
            const int h = n >> 6, d = n & 63;
            #pragma unroll
            for (int i = 0; i < 4; ++i) {
                const int m = m0 + wm * 64 + i * 16 + lq * 4; // b*2048+s base
                const int b = m >> 11, s = m & 2047;
                bf16x4 ov;
                #pragma unroll
                for (int r = 0; r < 4; ++r) ov[r] = (bf16)acc[i][j][r];
                *(bf16x4*)(Vtb + (((size_t)b * NHEAD + h) * DHEAD + d) * SEQL + s) = ov;
            }
        }
    }
}

// Output projection + residual (fp32 out). SWAPPED C: quad along n -> float4.
__global__ __launch_bounds__(256) void out128(
    const bf16* __restrict__ vec, const bf16* __restrict__ Wot,
    const bf16* __restrict__ qnb, float* __restrict__ out)
{
    __shared__ __align__(16) bf16 Asm[128 * 64];
    __shared__ __align__(16) bf16 Bsm[128 * 64];
    const int m0 = blockIdx.x * 128, n0 = blockIdx.y * 128;
    f32x4 acc[4][4] = {};
    gemm128_core(vec, Wot, m0, n0, true, acc, Asm, Bsm);
    const int t = threadIdx.x, L = t & 63, w = t >> 6;
    const int wm = w & 1, wn = w >> 1, lr = L & 15, lq = L >> 4;
    #pragma unroll
    for (int i = 0; i < 4; ++i) {
        const int m = m0 + wm * 64 + i * 16 + lr;            // row (fixed/lane)
        #pragma unroll
        for (int j = 0; j < 4; ++j) {
            const int n = n0 + wn * 64 + j * 16 + lq * 4;    // col base
            const size_t idx = (size_t)m * DM + n;
            const bf16x4 q4 = *(const bf16x4*)(qnb + idx);
            float4 ov;
            ov.x = acc[i][j][0] + (float)q4[0];
            ov.y = acc[i][j][1] + (float)q4[1];
            ov.z = acc[i][j][2] + (float)q4[2];
            ov.w = acc[i][j][3] + (float)q4[3];
            *(float4*)(out + idx) = ov;
        }
    }
}

// ---------------------------------------------------------------------------
// Flash attention v13 = v11 (R4/R6, verified ~109us) with ONE change: the
// per-tile __syncthreads() is replaced by {s_waitcnt lgkmcnt(0); s_barrier}.
// Rationale: __syncthreads forces vmcnt(0), draining the kreg/vreg global
// prefetch loads for tile kt+2 that nothing reads until next iteration's
// stage phase. LDS visibility here needs only lgkmcnt (staging is register
// ds_writes, not global_load_lds), so the barrier can keep the global loads
// in flight (T4 counted-vmcnt principle, minimal form). Hazard check: each
// wave drains its own ds_writes (lgkmcnt 0) before s_barrier -> all writes
// visible to all waves after it; kreg/vreg are consumed via register deps,
// for which the compiler inserts its own vmcnt waits.
__global__ __launch_bounds__(256) void flash_attn(
    const bf16* __restrict__ Qb, const bf16* __restrict__ Kb,
    const bf16* __restrict__ Vtb, const unsigned long long* __restrict__ mb,
    bf16* __restrict__ vec)
{
    __shared__ __align__(16) bf16 Ksm [2][64 * 72];    // [buf][slot(key)][d]
    __shared__ __align__(16) bf16 Vtsm[2][64 * 72];    // [buf][d][key]

    const int t = threadIdx.x, w = t >> 6, L = t & 63;
    const int lr = L & 15, lq = L >> 4;
    // XCD swizzle: slot = bid&7 fixed per bh -> K/V stay in one XCD's L2
    const int bid = blockIdx.x;
    const int slot = bid & 7, rest = bid >> 3;
    const int qblk = rest & 15;
    const int bh = ((rest >> 4) << 3) + slot;
    const int b = bh >> 4, h = bh & 15;
    const int q0 = qblk * 128 + w * 32;

    const bf16* Qh  = Qb  + (size_t)bh * SEQL * DHEAD;
    const bf16* Kh  = Kb  + (size_t)bh * SEQL * DHEAD;
    const bf16* Vth = Vtb + (size_t)bh * DHEAD * SEQL;

    // Q fragments: B-layout [n=qrow][k=d], resident. [qg][ks]
    bf16x8 qf[2][2];
    #pragma unroll
    for (int qg = 0; qg < 2; ++qg)
        #pragma unroll
        for (int ks = 0; ks < 2; ++ks)
            qf[qg][ks] = *(const bf16x8*)(Qh + (size_t)(q0 + qg * 16 + lr) * DHEAD + ks * 32 + lq * 8);

    // wave-uniform mask-word bases: qgrp stride = 32 kt * 16 words = 512
    const int qgrp0 = __builtin_amdgcn_readfirstlane(q0 >> 4);
    const unsigned long long* wm0 = mb + (size_t)qgrp0 * 512;
    const unsigned long long* wm1 = wm0 + 512;

    f32x4 o[4][2] = {};                      // O^T acc: [dgroup][qg]
    f32x4 lacc[2] = {};                      // row-sum acc via ones-MFMA

    const bf16 one = (bf16)1.0f;
    const bf16x8 ones8 = {one, one, one, one, one, one, one, one};
    const float fz = 0.0f;                   // VGPR zero for cndmask

    // staging: lane sr reads K row sr / Vt row sr; K goes to permuted slot row
    const int sr = t >> 2, sc = (t & 3) * 16;
    const int zrow = ((sr >> 2) & 1) * 32 + ((sr >> 5) & 1) * 16 + ((sr >> 3) & 3) * 4 + (sr & 3);
    constexpr int NT = SEQL / 64;
    bf16x8 kreg[2], vreg[2];

    // --- prologue: tile 0 -> regs -> buf0; tile 1 -> regs; one barrier
    kreg[0] = *(const bf16x8*)(Kh  + (size_t)sr * DHEAD + sc);
    kreg[1] = *(const bf16x8*)(Kh  + (size_t)sr * DHEAD + sc + 8);
    vreg[0] = *(const bf16x8*)(Vth + (size_t)sr * SEQL + sc);
    vreg[1] = *(const bf16x8*)(Vth + (size_t)sr * SEQL + sc + 8);
    *(bf16x8*)(Ksm[0]  + zrow * 72 + sc)     = kreg[0];
    *(bf16x8*)(Ksm[0]  + zrow * 72 + sc + 8) = kreg[1];
    *(bf16x8*)(Vtsm[0] + sr * 72 + sc)       = vreg[0];
    *(bf16x8*)(Vtsm[0] + sr * 72 + sc + 8)   = vreg[1];
    kreg[0] = *(const bf16x8*)(Kh  + (size_t)(64 + sr) * DHEAD + sc);
    kreg[1] = *(const bf16x8*)(Kh  + (size_t)(64 + sr) * DHEAD + sc + 8);
    vreg[0] = *(const bf16x8*)(Vth + (size_t)sr * SEQL + 64 + sc);
    vreg[1] = *(const bf16x8*)(Vth + (size_t)sr * SEQL + 64 + sc + 8);
    __syncthreads();

    for (int kt = 0; kt < NT; ++kt) {
        const int cur = kt & 1;
        const bf16* Kc = Ksm[cur];
        const bf16* Vc = Vtsm[cur];

        // ---- S^T = K·Q^T (K pre-scaled; rows permuted so C-layout = B-frag)
        f32x4 s[4][2] = {};
        #pragma unroll
        for (int ks = 0; ks < 2; ++ks) {
            bf16x8 kf[4];
            #pragma unroll
            for (int jj = 0; jj < 4; ++jj)
                kf[jj] = *(const bf16x8*)(Kc + (jj * 16 + lr) * 72 + ks * 32 + lq * 8);
            __builtin_amdgcn_s_setprio(1);
            #pragma unroll
            for (int jj = 0; jj < 4; ++jj)
                #pragma unroll
                for (int qg = 0; qg < 2; ++qg)
                    s[jj][qg] = MFMA16(kf[jj], qf[qg][ks], s[jj][qg], 0, 0, 0);
            __builtin_amdgcn_s_setprio(0);
        }

        // ---- stage tile kt+1 (regs, loaded last iter) -> alt buffer; these
        // ds_writes drain under the exp/cndmask VALU below. Then prefetch kt+2.
        if (kt + 1 < NT) {
            bf16* Ka = Ksm[cur ^ 1];
            bf16* Va = Vtsm[cur ^ 1];
            *(bf16x8*)(Ka + zrow * 72 + sc)     = kreg[0];
            *(bf16x8*)(Ka + zrow * 72 + sc + 8) = kreg[1];
            *(bf16x8*)(Va + sr * 72 + sc)       = vreg[0];
            *(bf16x8*)(Va + sr * 72 + sc + 8)   = vreg[1];
            if (kt + 2 < NT) {
                const int kb2 = (kt + 2) * 64;
                kreg[0] = *(const bf16x8*)(Kh  + (size_t)(kb2 + sr) * DHEAD + sc);
                kreg[1] = *(const bf16x8*)(Kh  + (size_t)(kb2 + sr) * DHEAD + sc + 8);
                vreg[0] = *(const bf16x8*)(Vth + (size_t)sr * SEQL + kb2 + sc);
                vreg[1] = *(const bf16x8*)(Vth + (size_t)sr * SEQL + kb2 + sc + 8);
            }
        }

        // ---- exp2 -> sgpr-mask cndmask -> pack.
        // s[jj][qg][r] holds key = (jj&1)*32 + lq*8 + (jj>>1)*4 + r; word
        // wp[jj*4+r] bit L masks exactly this register's lane-L element.
        bf16x8 pf[2][2];
        #pragma unroll
        for (int qg = 0; qg < 2; ++qg) {
            const unsigned long long* wp = (qg ? wm1 : wm0) + kt * 16;
            #pragma unroll
            for (int ks = 0; ks < 2; ++ks) {
                bf16x8 pv;
                #pragma unroll
                for (int r = 0; r < 4; ++r) {
                    float e0 = __builtin_amdgcn_exp2f(s[ks][qg][r]);
                    float e1 = __builtin_amdgcn_exp2f(s[2 + ks][qg][r]);
                    float z0, z1;
                    asm("v_cndmask_b32 %0, %1, %2, %3"
                        : "=v"(z0) : "v"(e0), "v"(fz), "s"(wp[ks * 4 + r]));
                    asm("v_cndmask_b32 %0, %1, %2, %3"
                        : "=v"(z1) : "v"(e1), "v"(fz), "s"(wp[(2 + ks) * 4 + r]));
                    pv[r]     = (bf16)z0;
                    pv[4 + r] = (bf16)z1;
                }
                pf[qg][ks] = pv;
            }
        }

        // ---- l += 1·P  and  O^T += V^T·P  (P in registers, reads cur buf)
        __builtin_amdgcn_s_setprio(1);
        #pragma unroll
        for (int ks = 0; ks < 2; ++ks) {
            #pragma unroll
            for (int qg = 0; qg < 2; ++qg)
                lacc[qg] = MFMA16(ones8, pf[qg][ks], lacc[qg], 0, 0, 0);
            #pragma unroll
            for (int dg = 0; dg < 4; ++dg) {
                bf16x8 vf = *(const bf16x8*)(Vc + (dg * 16 + lr) * 72 + ks * 32 + lq * 8);
                #pragma unroll
                for (int qg = 0; qg < 2; ++qg)
                    o[dg][qg] = MFMA16(vf, pf[qg][ks], o[dg][qg], 0, 0, 0);
            }
        }
        __builtin_amdgcn_s_setprio(0);

        // per-tile barrier WITHOUT vmcnt drain: LDS writes need lgkmcnt only;
        // kt+2 global prefetch loads stay in flight across the barrier.
        if (kt + 1 < NT) {
            asm volatile("s_waitcnt lgkmcnt(0)" ::: "memory");
            __builtin_amdgcn_s_barrier();
        }
    }

    // ---- epilogue: vec[b][s][h*64+d]; lane qrow=lr, d=dg*16+lq*4+r -> b64 stores
    #pragma unroll
    for (int qg = 0; qg < 2; ++qg) {
        const float rl = 1.0f / lacc[qg][0];
        const size_t rowb = ((size_t)b * SEQL + q0 + qg * 16 + lr) * DM + h * DHEAD;
        #pragma unroll
        for (int dg = 0; dg < 4; ++dg) {
            bf16x4 ov;
            #pragma unroll
            for (int r = 0; r < 4; ++r) ov[r] = (bf16)(o[dg][qg][r] * rl);
            *(bf16x4*)(vec + rowb + dg * 16 + lq * 4) = ov;
        }
    }
}

// ---------------------------------------------------------------------------
extern "C" void kernel_launch(void* const* d_in, const int* in_sizes, int n_in,
                              void* d_out, int out_size, void* d_ws, size_t ws_size,
                              hipStream_t stream)
{
    const float* qin   = (const float*)d_in[0];
    const void*  mask  = d_in[1];
    const float* Wq    = (const float*)d_in[2];
    const float* Wk    = (const float*)d_in[3];
    const float* Wv    = (const float*)d_in[4];
    const float* Wo    = (const float*)d_in[5];
    const float* gamma = (const float*)d_in[6];
    const float* beta  = (const float*)d_in[7];
    float* out = (float*)d_out;

    char* w = (char*)d_ws;
    int*  flag = (int*)w;
    bf16* qnb  = (bf16*)(w + 256);                 // 8192x1024 bf16  (16 MB)
    bf16* Wt   = qnb + (size_t)8192 * 1024;        // 4x 1024x1024 bf16 (8 MB)
    bf16* Qb   = Wt + (size_t)4 * 1024 * 1024;     // (b,h,s,d)  (16 MB)
    bf16* Kb   = Qb + (size_t)8192 * 1024;         // (b,h,s,d)  (16 MB)
    bf16* Vtb  = Kb + (size_t)8192 * 1024;         // (b,h,d,s)  (16 MB)
    bf16* vec  = Vtb + (size_t)8192 * 1024;        // (b,s,h*d)  (16 MB)
    unsigned long long* rbits  = (unsigned long long*)(vec + (size_t)8192 * 1024); // 512 KB
    unsigned long long* mwords = rbits + 65536;                                    // 512 KB

    detect_mask<<<1, 256, 0, stream>>>((const unsigned int*)mask, flag);
    prep_bits<<<SEQL * (SEQL / 64) / 4, 256, 0, stream>>>(mask, flag, rbits);
    prep_words<<<1024, 256, 0, stream>>>(rbits, mwords);
    ln_kernel<<<8192, 256, 0, stream>>>(qin, gamma, beta, qnb);
    cvt_w<<<dim3(32, 32, 4), dim3(32, 8), 0, stream>>>(Wq, Wk, Wv, Wo, Wt);
    qkv128<<<dim3(64, 24), 256, 0, stream>>>(qnb, Wt, Qb, Kb, Vtb);
    flash_attn<<<1024, 256, 0, stream>>>(Qb, Kb, Vtb, mwords, vec);
    out128<<<dim3(64, 8), 256, 0, stream>>>(vec, Wt + (size_t)3 * 1024 * 1024, qnb, out);
}

// Round 9
// 291.876 us; speedup vs baseline: 1.1506x; 1.1162x over previous
//
#include <hip/hip_runtime.h>

typedef __bf16 bf16;
typedef __bf16 bf16x8 __attribute__((ext_vector_type(8)));
typedef __bf16 bf16x4 __attribute__((ext_vector_type(4)));
typedef float  f32x4  __attribute__((ext_vector_type(4)));

#define MFMA16 __builtin_amdgcn_mfma_f32_16x16x32_bf16

static constexpr int   BSZ   = 4;
static constexpr int   SEQL  = 2048;
static constexpr int   DM    = 1024;
static constexpr int   NHEAD = 16;
static constexpr int   DHEAD = 64;
static constexpr float SCL2  = 0.125f * 1.44269504f;   // folded into Wk at cvt

// async global->LDS, 16B per lane; LDS dest = wave-uniform base + lane*16
__device__ __forceinline__ void glds16(bf16* lds, const bf16* g) {
    __builtin_amdgcn_global_load_lds(
        (const __attribute__((address_space(1))) unsigned int*)g,
        (__attribute__((address_space(3))) unsigned int*)lds, 16, 0, 0);
}

// ---------------------------------------------------------------------------
// Mask dtype detection: flag 0=int32{0,1}, 1=byte, 2=float32, 3=bf16
__global__ void detect_mask(const unsigned int* __restrict__ m, int* __restrict__ flag) {
    __shared__ int ok[4];
    if (threadIdx.x < 4) ok[threadIdx.x] = 1;
    __syncthreads();
    for (int i = 0; i < 16; ++i) {
        unsigned int w = m[threadIdx.x * 16 + i];
        if (!(w == 0u || w == 1u)) ok[0] = 0;
        if (w & 0xFEFEFEFEu) ok[1] = 0;
        if (!(w == 0u || w == 0x3F800000u)) ok[2] = 0;
        unsigned lo = w & 0xFFFFu, hi = w >> 16;
        if (!((lo == 0u || lo == 0x3F80u) && (hi == 0u || hi == 0x3F80u))) ok[3] = 0;
    }
    __syncthreads();
    if (threadIdx.x == 0)
        *flag = ok[0] ? 0 : (ok[1] ? 1 : (ok[2] ? 2 : 3));
}

__device__ __forceinline__ bool mask_at(const void* m, int fl, long idx) {
    if (fl == 0) return ((const int*)m)[idx] != 0;
    if (fl == 1) return ((const unsigned char*)m)[idx] != 0;
    if (fl == 2) return ((const float*)m)[idx] != 0.0f;
    return ((const unsigned short*)m)[idx] != 0;
}

// mask -> row bit matrix: rb[row*32+kt] bit k = mask[row][kt*64+k]. One ballot/wave.
__global__ __launch_bounds__(256) void prep_bits(const void* __restrict__ mask,
                                                 const int* __restrict__ flagp,
                                                 unsigned long long* __restrict__ rb) {
    const int fl = *flagp;
    const int word = blockIdx.x * 4 + (threadIdx.x >> 6);
    const long base = (long)word * 64 + (threadIdx.x & 63);
    unsigned long long b = __ballot(mask_at(mask, fl, base));
    if ((threadIdx.x & 63) == 0) rb[word] = b;
}

// Rearrange row bits into MFMA-register layout words:
// wm[(qgrp*32+kt)*16 + jj*4+r] bit L = mask[qgrp*16+(L&15)][kt*64+(jj&1)*32+(L>>4)*8+(jj>>1)*4+r]
// so in flash_attn one u64 word masks exactly one (qg,jj,r) output register via
// a single sgpr-pair v_cndmask (bit index == lane id).
__global__ __launch_bounds__(256) void prep_words(
    const unsigned long long* __restrict__ rb, unsigned long long* __restrict__ wm)
{
    const int t = threadIdx.x, L = t & 63, w = t >> 6;
    const int pair = blockIdx.x * 4 + w;            // qgrp*32 + kt, 0..4095
    const int qgrp = pair >> 5, kt = pair & 31;
    const unsigned long long r0 = rb[(size_t)(qgrp * 16 + (L & 15)) * 32 + kt];
    const int lq = L >> 4;
    unsigned long long myw = 0;
    #pragma unroll
    for (int jr = 0; jr < 16; ++jr) {
        const int jj = jr >> 2, r = jr & 3;
        const int bitpos = (jj & 1) * 32 + lq * 8 + (jj >> 1) * 4 + r;
        unsigned long long bal = __ballot(((r0 >> bitpos) & 1ull) != 0ull);
        if (L == jr) myw = bal;
    }
    if (L < 16) wm[(size_t)pair * 16 + L] = myw;
}

// ---------------------------------------------------------------------------
// LayerNorm: one block per row of 1024. fp32 compute, bf16 out.
__global__ __launch_bounds__(256) void ln_kernel(
    const float* __restrict__ x, const float* __restrict__ g,
    const float* __restrict__ bta, bf16* __restrict__ y)
{
    const int row = blockIdx.x, t = threadIdx.x;
    const float4 v = ((const float4*)(x + (size_t)row * DM))[t];
    float s  = v.x + v.y + v.z + v.w;
    float ss = v.x * v.x + v.y * v.y + v.z * v.z + v.w * v.w;
    for (int m = 32; m >= 1; m >>= 1) { s += __shfl_xor(s, m); ss += __shfl_xor(ss, m); }
    __shared__ float red[8];
    const int w = t >> 6, L = t & 63;
    if (L == 0) { red[w] = s; red[4 + w] = ss; }
    __syncthreads();
    s  = red[0] + red[1] + red[2] + red[3];
    ss = red[4] + red[5] + red[6] + red[7];
    const float mu = s * (1.0f / DM);
    const float var = ss * (1.0f / DM) - mu * mu;
    const float r = rsqrtf(var + 1e-5f);
    const float4 gv = ((const float4*)g)[t];
    const float4 bv = ((const float4*)bta)[t];
    bf16x4 o;
    o[0] = (bf16)((v.x - mu) * r * gv.x + bv.x);
    o[1] = (bf16)((v.y - mu) * r * gv.y + bv.y);
    o[2] = (bf16)((v.z - mu) * r * gv.z + bv.z);
    o[3] = (bf16)((v.w - mu) * r * gv.w + bv.w);
    ((bf16x4*)(y + (size_t)row * DM))[t] = o;
}

// ---------------------------------------------------------------------------
// Transpose+convert 4 weight matrices (1024x1024 f32, KxN) into bf16 NxK.
// Wk (z==1) is pre-scaled by SCALE*log2e so flash scores are in log2 domain.
__global__ void cvt_w(const float* __restrict__ Wq, const float* __restrict__ Wk,
                      const float* __restrict__ Wv, const float* __restrict__ Wo,
                      bf16* __restrict__ Wt)
{
    __shared__ float tile[32][33];
    const int z = blockIdx.z;
    const float* src = (z == 0) ? Wq : (z == 1) ? Wk : (z == 2) ? Wv : Wo;
    const float scl = (z == 1) ? SCL2 : 1.0f;
    bf16* dst = Wt + (size_t)z * DM * DM;
    const int tx = threadIdx.x, ty = threadIdx.y;
    const int nIn = blockIdx.x * 32 + tx;
    const int kIn = blockIdx.y * 32;
    for (int i = 0; i < 32; i += 8)
        tile[ty + i][tx] = src[(size_t)(kIn + ty + i) * DM + nIn];
    __syncthreads();
    const int nOut = blockIdx.x * 32;
    const int kOut = blockIdx.y * 32 + tx;
    for (int i = 0; i < 32; i += 8)
        dst[(size_t)(nOut + ty + i) * DM + kOut] = (bf16)(tile[tx][ty + i] * scl);
}

// ---------------------------------------------------------------------------
// 128x128 GEMM core, BK=64 (R6, verified): A (MxK rm), Bt (NxK rm),
// global_load_lds staging. LDS rows XOR-swizzled by (row&7) on the 16B slot:
// store side pre-swizzles the GLOBAL source column (glds16 dest stays linear),
// read side applies the same XOR -> b128 8-cycle floor.
// C-layout per `swapped`: unswapped: m <- lq*4+r, n <- lr;
// swapped: m <- lr, n <- lq*4+r (quad along the contiguous output axis).
__device__ __forceinline__ void gemm128_core(
    const bf16* __restrict__ A, const bf16* __restrict__ Bt,
    int m0, int n0, bool swapped, f32x4 acc[4][4], bf16* Asm, bf16* Bsm)
{
    const int t = threadIdx.x, w = t >> 6, L = t & 63;
    const int lr = L & 15, lq = L >> 4;
    const int wm = w & 1, wn = w >> 1;
    const int srow = L >> 3;
    const int scol = ((L & 7) ^ (L >> 3)) * 8;
    const bf16* Ab = A  + (size_t)(m0 + w * 32 + srow) * DM + scol;
    const bf16* Bb = Bt + (size_t)(n0 + w * 32 + srow) * DM + scol;
    bf16* AsmW = Asm + (w * 32) * 64;
    bf16* BsmW = Bsm + (w * 32) * 64;
    for (int kk = 0; kk < DM; kk += 64) {
        __syncthreads();
        glds16(AsmW,           Ab + kk);
        glds16(AsmW +  8 * 64, Ab + (size_t) 8 * DM + kk);
        glds16(AsmW + 16 * 64, Ab + (size_t)16 * DM + kk);
        glds16(AsmW + 24 * 64, Ab + (size_t)24 * DM + kk);
        glds16(BsmW,           Bb + kk);
        glds16(BsmW +  8 * 64, Bb + (size_t) 8 * DM + kk);
        glds16(BsmW + 16 * 64, Bb + (size_t)16 * DM + kk);
        glds16(BsmW + 24 * 64, Bb + (size_t)24 * DM + kk);
        __syncthreads();
        #pragma unroll
        for (int ks = 0; ks < 2; ++ks) {
            bf16x8 af[4], bf_[4];
            #pragma unroll
            for (int i = 0; i < 4; ++i) {
                const int ra = wm * 64 + i * 16 + lr;
                af[i] = *(const bf16x8*)(Asm + ra * 64 + ((((ks << 2) | lq) ^ (lr & 7)) << 3));
            }
            #pragma unroll
            for (int j = 0; j < 4; ++j) {
                const int rb2 = wn * 64 + j * 16 + lr;
                bf_[j] = *(const bf16x8*)(Bsm + rb2 * 64 + ((((ks << 2) | lq) ^ (lr & 7)) << 3));
            }
            if (!swapped) {
                #pragma unroll
                for (int i = 0; i < 4; ++i)
                    #pragma unroll
                    for (int j = 0; j < 4; ++j)
                        acc[i][j] = MFMA16(af[i], bf_[j], acc[i][j], 0, 0, 0);
            } else {
                #pragma unroll
                for (int i = 0; i < 4; ++i)
                    #pragma unroll
                    for (int j = 0; j < 4; ++j)
                        acc[i][j] = MFMA16(bf_[j], af[i], acc[i][j], 0, 0, 0);
            }
        }
    }
}

// Fused QKV projection, one dispatch: y -> (z = y>>3, n0 = (y&7)*128).
// z=0,1 -> Q,K in (b,h,s,d) via SWAPPED C (quad along d -> bf16x4 stores);
// z=2   -> V^T in (b,h,d,s) via UNSWAPPED C (quad along s -> bf16x4 stores).
__global__ __launch_bounds__(256) void qkv128(
    const bf16* __restrict__ qn, const bf16* __restrict__ Wt,
    bf16* __restrict__ Qb, bf16* __restrict__ Kb, bf16* __restrict__ Vtb)
{
    __shared__ __align__(16) bf16 Asm[128 * 64];
    __shared__ __align__(16) bf16 Bsm[128 * 64];
    const int ny = blockIdx.y;
    const int z = ny >> 3;
    const int m0 = blockIdx.x * 128, n0 = (ny & 7) * 128;
    f32x4 acc[4][4] = {};
    gemm128_core(qn, Wt + (size_t)z * DM * DM, m0, n0, z < 2, acc, Asm, Bsm);
    const int t = threadIdx.x, L = t & 63, w = t >> 6;
    const int wm = w & 1, wn = w >> 1, lr = L & 15, lq = L >> 4;
    if (z < 2) {
        bf16* dst = z ? Kb : Qb;
        #pragma unroll
        for (int i = 0; i < 4; ++i) {
            const int m = m0 + wm * 64 + i * 16 + lr;        // b*2048+s (fixed/lane)
            const int b = m >> 11, s = m & 2047;
            #pragma unroll
            for (int j = 0; j < 4; ++j) {
                const int n = n0 + wn * 64 + j * 16 + lq * 4; // h*64+d base
                const int h = n >> 6, d = n & 63;
                bf16x4 ov;
                #pragma unroll
                for (int r = 0; r < 4; ++r) ov[r] = (bf16)acc[i][j][r];
                *(bf16x4*)(dst + (((size_t)b * NHEAD + h) * SEQL + s) * DHEAD + d) = ov;
            }
        }
    } else {
        #pragma unroll
        for (int j = 0; j < 4; ++j) {
            const int n = n0 + wn * 64 + j * 16 + lr;        // h*64+d (fixed/lane)
            const int h = n >> 6, d = n & 63;
            #pragma unroll
            for (int i = 0; i < 4; ++i) {
                const int m = m0 + wm * 64 + i * 16 + lq * 4; // b*2048+s base
                const int b = m >> 11, s = m & 2047;
                bf16x4 ov;
                #pragma unroll
                for (int r = 0; r < 4; ++r) ov[r] = (bf16)acc[i][j][r];
                *(bf16x4*)(Vtb + (((size_t)b * NHEAD + h) * DHEAD + d) * SEQL + s) = ov;
            }
        }
    }
}

// Output projection + residual (fp32 out). SWAPPED C: quad along n -> float4.
__global__ __launch_bounds__(256) void out128(
    const bf16* __restrict__ vec, const bf16* __restrict__ Wot,
    const bf16* __restrict__ qnb, float* __restrict__ out)
{
    __shared__ __align__(16) bf16 Asm[128 * 64];
    __shared__ __align__(16) bf16 Bsm[128 * 64];
    const int m0 = blockIdx.x * 128, n0 = blockIdx.y * 128;
    f32x4 acc[4][4] = {};
    gemm128_core(vec, Wot, m0, n0, true, acc, Asm, Bsm);
    const int t = threadIdx.x, L = t & 63, w = t >> 6;
    const int wm = w & 1, wn = w >> 1, lr = L & 15, lq = L >> 4;
    #pragma unroll
    for (int i = 0; i < 4; ++i) {
        const int m = m0 + wm * 64 + i * 16 + lr;            // row (fixed/lane)
        #pragma unroll
        for (int j = 0; j < 4; ++j) {
            const int n = n0 + wn * 64 + j * 16 + lq * 4;    // col base
            const size_t idx = (size_t)m * DM + n;
            const bf16x4 q4 = *(const bf16x4*)(qnb + idx);
            float4 ov;
            ov.x = acc[i][j][0] + (float)q4[0];
            ov.y = acc[i][j][1] + (float)q4[1];
            ov.z = acc[i][j][2] + (float)q4[2];
            ov.w = acc[i][j][3] + (float)q4[3];
            *(float4*)(out + idx) = ov;
        }
    }
}

// ---------------------------------------------------------------------------
// Flash attention v14: v13 schedule (verified) widened to 8 WAVES PER BLOCK
// (512 thr, 256 q-rows/block, grid 512). Occupancy counter showed ~2 resident
// blocks/CU (~21%) at 4 waves/block -> only ~1.7 waves/SIMD to hide the
// QK->exp->PV chain. Same 36KB LDS and same one-barrier-per-tile schedule,
// but 2 resident blocks now carry 16 waves/CU, and per-CU staging traffic
// halves (one tile-stage feeds 2x compute). Staging remap: 8 threads/row
// (sr=t>>3, sc=(t&7)*8), single bf16x8 each for K and V. All fragment math,
// zrow permutation, mask words, buffer parities, epilogue: unchanged.
__global__ __launch_bounds__(512) void flash_attn(
    const bf16* __restrict__ Qb, const bf16* __restrict__ Kb,
    const bf16* __restrict__ Vtb, const unsigned long long* __restrict__ mb,
    bf16* __restrict__ vec)
{
    __shared__ __align__(16) bf16 Ksm [2][64 * 72];    // [buf][slot(key)][d]
    __shared__ __align__(16) bf16 Vtsm[2][64 * 72];    // [buf][d][key]

    const int t = threadIdx.x, w = t >> 6, L = t & 63;
    const int lr = L & 15, lq = L >> 4;
    // XCD swizzle: slot = bid&7 fixed per bh -> K/V stay in one XCD's L2
    const int bid = blockIdx.x;
    const int slot = bid & 7, rest = bid >> 3;      // rest 0..63
    const int qblk = rest & 7;                      // 8 q-blocks of 256 rows
    const int bh = ((rest >> 3) << 3) + slot;       // 0..63
    const int b = bh >> 4, h = bh & 15;
    const int q0 = qblk * 256 + w * 32;

    const bf16* Qh  = Qb  + (size_t)bh * SEQL * DHEAD;
    const bf16* Kh  = Kb  + (size_t)bh * SEQL * DHEAD;
    const bf16* Vth = Vtb + (size_t)bh * DHEAD * SEQL;

    // Q fragments: B-layout [n=qrow][k=d], resident. [qg][ks]
    bf16x8 qf[2][2];
    #pragma unroll
    for (int qg = 0; qg < 2; ++qg)
        #pragma unroll
        for (int ks = 0; ks < 2; ++ks)
            qf[qg][ks] = *(const bf16x8*)(Qh + (size_t)(q0 + qg * 16 + lr) * DHEAD + ks * 32 + lq * 8);

    // wave-uniform mask-word bases: qgrp stride = 32 kt * 16 words = 512
    const int qgrp0 = __builtin_amdgcn_readfirstlane(q0 >> 4);
    const unsigned long long* wm0 = mb + (size_t)qgrp0 * 512;
    const unsigned long long* wm1 = wm0 + 512;

    f32x4 o[4][2] = {};                      // O^T acc: [dgroup][qg]
    f32x4 lacc[2] = {};                      // row-sum acc via ones-MFMA

    const bf16 one = (bf16)1.0f;
    const bf16x8 ones8 = {one, one, one, one, one, one, one, one};
    const float fz = 0.0f;                   // VGPR zero for cndmask

    // staging: 8 threads/row; lane sr reads K row sr / Vt row sr; K goes to
    // the permuted slot row (zrow). 512 threads cover 64 rows x 64 cols.
    const int sr = t >> 3, sc = (t & 7) * 8;
    const int zrow = ((sr >> 2) & 1) * 32 + ((sr >> 5) & 1) * 16 + ((sr >> 3) & 3) * 4 + (sr & 3);
    constexpr int NT = SEQL / 64;
    bf16x8 kreg, vreg;

    // --- prologue: tile 0 -> regs -> buf0; tile 1 -> regs; one barrier
    kreg = *(const bf16x8*)(Kh  + (size_t)sr * DHEAD + sc);
    vreg = *(const bf16x8*)(Vth + (size_t)sr * SEQL + sc);
    *(bf16x8*)(Ksm[0]  + zrow * 72 + sc) = kreg;
    *(bf16x8*)(Vtsm[0] + sr * 72 + sc)   = vreg;
    kreg = *(const bf16x8*)(Kh  + (size_t)(64 + sr) * DHEAD + sc);
    vreg = *(const bf16x8*)(Vth + (size_t)sr * SEQL + 64 + sc);
    __syncthreads();

    for (int kt = 0; kt < NT; ++kt) {
        const int cur = kt & 1;
        const bf16* Kc = Ksm[cur];
        const bf16* Vc = Vtsm[cur];

        // ---- S^T = K·Q^T (K pre-scaled; rows permuted so C-layout = B-frag)
        f32x4 s[4][2] = {};
        #pragma unroll
        for (int ks = 0; ks < 2; ++ks) {
            bf16x8 kf[4];
            #pragma unroll
            for (int jj = 0; jj < 4; ++jj)
                kf[jj] = *(const bf16x8*)(Kc + (jj * 16 + lr) * 72 + ks * 32 + lq * 8);
            __builtin_amdgcn_s_setprio(1);
            #pragma unroll
            for (int jj = 0; jj < 4; ++jj)
                #pragma unroll
                for (int qg = 0; qg < 2; ++qg)
                    s[jj][qg] = MFMA16(kf[jj], qf[qg][ks], s[jj][qg], 0, 0, 0);
            __builtin_amdgcn_s_setprio(0);
        }

        // ---- stage tile kt+1 (regs, loaded last iter) -> alt buffer; these
        // ds_writes drain under the exp/cndmask VALU below. Then prefetch kt+2.
        if (kt + 1 < NT) {
            *(bf16x8*)(Ksm [cur ^ 1] + zrow * 72 + sc) = kreg;
            *(bf16x8*)(Vtsm[cur ^ 1] + sr * 72 + sc)   = vreg;
            if (kt + 2 < NT) {
                const int kb2 = (kt + 2) * 64;
                kreg = *(const bf16x8*)(Kh  + (size_t)(kb2 + sr) * DHEAD + sc);
                vreg = *(const bf16x8*)(Vth + (size_t)sr * SEQL + kb2 + sc);
            }
        }

        // ---- exp2 -> sgpr-mask cndmask -> pack.
        // s[jj][qg][r] holds key = (jj&1)*32 + lq*8 + (jj>>1)*4 + r; word
        // wp[jj*4+r] bit L masks exactly this register's lane-L element.
        bf16x8 pf[2][2];
        #pragma unroll
        for (int qg = 0; qg < 2; ++qg) {
            const unsigned long long* wp = (qg ? wm1 : wm0) + kt * 16;
            #pragma unroll
            for (int ks = 0; ks < 2; ++ks) {
                bf16x8 pv;
                #pragma unroll
                for (int r = 0; r < 4; ++r) {
                    float e0 = __builtin_amdgcn_exp2f(s[ks][qg][r]);
                    float e1 = __builtin_amdgcn_exp2f(s[2 + ks][qg][r]);
                    float z0, z1;
                    asm("v_cndmask_b32 %0, %1, %2, %3"
                        : "=v"(z0) : "v"(e0), "v"(fz), "s"(wp[ks * 4 + r]));
                    asm("v_cndmask_b32 %0, %1, %2, %3"
                        : "=v"(z1) : "v"(e1), "v"(fz), "s"(wp[(2 + ks) * 4 + r]));
                    pv[r]     = (bf16)z0;
                    pv[4 + r] = (bf16)z1;
                }
                pf[qg][ks] = pv;
            }
        }

        // ---- l += 1·P  and  O^T += V^T·P  (P in registers, reads cur buf)
        __builtin_amdgcn_s_setprio(1);
        #pragma unroll
        for (int ks = 0; ks < 2; ++ks) {
            #pragma unroll
            for (int qg = 0; qg < 2; ++qg)
                lacc[qg] = MFMA16(ones8, pf[qg][ks], lacc[qg], 0, 0, 0);
            #pragma unroll
            for (int dg = 0; dg < 4; ++dg) {
                bf16x8 vf = *(const bf16x8*)(Vc + (dg * 16 + lr) * 72 + ks * 32 + lq * 8);
                #pragma unroll
                for (int qg = 0; qg < 2; ++qg)
                    o[dg][qg] = MFMA16(vf, pf[qg][ks], o[dg][qg], 0, 0, 0);
            }
        }
        __builtin_amdgcn_s_setprio(0);

        // per-tile barrier WITHOUT vmcnt drain: LDS writes need lgkmcnt only;
        // kt+2 global prefetch loads stay in flight across the barrier.
        if (kt + 1 < NT) {
            asm volatile("s_waitcnt lgkmcnt(0)" ::: "memory");
            __builtin_amdgcn_s_barrier();
        }
    }

    // ---- epilogue: vec[b][s][h*64+d]; lane qrow=lr, d=dg*16+lq*4+r -> b64 stores
    #pragma unroll
    for (int qg = 0; qg < 2; ++qg) {
        const float rl = 1.0f / lacc[qg][0];
        const size_t rowb = ((size_t)b * SEQL + q0 + qg * 16 + lr) * DM + h * DHEAD;
        #pragma unroll
        for (int dg = 0; dg < 4; ++dg) {
            bf16x4 ov;
            #pragma unroll
            for (int r = 0; r < 4; ++r) ov[r] = (bf16)(o[dg][qg][r] * rl);
            *(bf16x4*)(vec + rowb + dg * 16 + lq * 4) = ov;
        }
    }
}

// ---------------------------------------------------------------------------
extern "C" void kernel_launch(void* const* d_in, const int* in_sizes, int n_in,
                              void* d_out, int out_size, void* d_ws, size_t ws_size,
                              hipStream_t stream)
{
    const float* qin   = (const float*)d_in[0];
    const void*  mask  = d_in[1];
    const float* Wq    = (const float*)d_in[2];
    const float* Wk    = (const float*)d_in[3];
    const float* Wv    = (const float*)d_in[4];
    const float* Wo    = (const float*)d_in[5];
    const float* gamma = (const float*)d_in[6];
    const float* beta  = (const float*)d_in[7];
    float* out = (float*)d_out;

    char* w = (char*)d_ws;
    int*  flag = (int*)w;
    bf16* qnb  = (bf16*)(w + 256);                 // 8192x1024 bf16  (16 MB)
    bf16* Wt   = qnb + (size_t)8192 * 1024;        // 4x 1024x1024 bf16 (8 MB)
    bf16* Qb   = Wt + (size_t)4 * 1024 * 1024;     // (b,h,s,d)  (16 MB)
    bf16* Kb   = Qb + (size_t)8192 * 1024;         // (b,h,s,d)  (16 MB)
    bf16* Vtb  = Kb + (size_t)8192 * 1024;         // (b,h,d,s)  (16 MB)
    bf16* vec  = Vtb + (size_t)8192 * 1024;        // (b,s,h*d)  (16 MB)
    unsigned long long* rbits  = (unsigned long long*)(vec + (size_t)8192 * 1024); // 512 KB
    unsigned long long* mwords = rbits + 65536;                                    // 512 KB

    detect_mask<<<1, 256, 0, stream>>>((const unsigned int*)mask, flag);
    prep_bits<<<SEQL * (SEQL / 64) / 4, 256, 0, stream>>>(mask, flag, rbits);
    prep_words<<<1024, 256, 0, stream>>>(rbits, mwords);
    ln_kernel<<<8192, 256, 0, stream>>>(qin, gamma, beta, qnb);
    cvt_w<<<dim3(32, 32, 4), dim3(32, 8), 0, stream>>>(Wq, Wk, Wv, Wo, Wt);
    qkv128<<<dim3(64, 24), 256, 0, stream>>>(qnb, Wt, Qb, Kb, Vtb);
    flash_attn<<<512, 512, 0, stream>>>(Qb, Kb, Vtb, mwords, vec);
    out128<<<dim3(64, 8), 256, 0, stream>>>(vec, Wt + (size_t)3 * 1024 * 1024, qnb, out);
}